// Round 1
// baseline (5009.606 us; speedup 1.0000x reference)
//
#include <hip/hip_runtime.h>
#include <hip/hip_bf16.h>
#include <stddef.h>

#define NN    8
#define CIN   256
#define TT    128
#define VV    128
#define OUTC  512
#define HH    8
#define DD    64

typedef __hip_bfloat16 bf16;

// -------------------------------------------------------------------------
// Kernel 1: fused QKV projection + attention for one (n,t) per block.
//   x  : (N, CIN, T, V) fp32
//   wq/wk/wv : (OUT, CIN) fp32
//   o_ws : (N, OUT, T, V) bf16   -- o_arr[n, h*64+d, t, v] = o[n,t,h,v,d]
// LDS: two 32KB fp32 buffers (qT/vT and kT/os), total 64 KB.
// Thread mapping:
//   projection: pv = (tid&31)*4 (4 v cols), pd = (tid>>5)*8 (8 d rows)
//   attention : vq = tid>>1 (query row), half = tid&1 (w-half), partner = lane^1
// -------------------------------------------------------------------------
__global__ __launch_bounds__(256, 2)
void fused_qkv_attn_kernel(const float* __restrict__ x,
                           const float* __restrict__ wq,
                           const float* __restrict__ wk,
                           const float* __restrict__ wv,
                           bf16* __restrict__ o_ws)
{
    __shared__ __align__(16) float bufA[VV * DD];  // qT[v][d], later vT[w][d]
    __shared__ __align__(16) float bufB[VV * DD];  // kT[w][d], later os (bf16 alias)

    const int blk = blockIdx.x;
    const int n   = blk >> 7;
    const int t   = blk & 127;
    const int tid = threadIdx.x;

    const int pv = (tid & 31) << 2;   // projection v base
    const int pd = (tid >> 5) << 3;   // projection d base

    const int vq   = tid >> 1;        // attention query row
    const int half = tid & 1;
    const int wb   = half << 6;       // this thread's w range base

    const float* xbase = x + ((size_t)n * CIN * TT + (size_t)t) * VV;

    for (int h = 0; h < HH; ++h) {
        const int oc = h * DD;

        // ---------------- Q,K projection (fp32) ----------------
        float aq[8][4], ak[8][4];
        #pragma unroll
        for (int i = 0; i < 8; ++i)
            #pragma unroll
            for (int j = 0; j < 4; ++j) { aq[i][j] = 0.f; ak[i][j] = 0.f; }
        {
            const float* xp  = xbase + pv;
            const float* wqp = wq + (size_t)(oc + pd) * CIN;
            const float* wkp = wk + (size_t)(oc + pd) * CIN;
            for (int c = 0; c < CIN; ++c) {
                const float4 xv = *(const float4*)xp;
                #pragma unroll
                for (int i = 0; i < 8; ++i) {
                    const float a = wqp[i * CIN + c];
                    const float b = wkp[i * CIN + c];
                    aq[i][0] = fmaf(a, xv.x, aq[i][0]);
                    aq[i][1] = fmaf(a, xv.y, aq[i][1]);
                    aq[i][2] = fmaf(a, xv.z, aq[i][2]);
                    aq[i][3] = fmaf(a, xv.w, aq[i][3]);
                    ak[i][0] = fmaf(b, xv.x, ak[i][0]);
                    ak[i][1] = fmaf(b, xv.y, ak[i][1]);
                    ak[i][2] = fmaf(b, xv.z, ak[i][2]);
                    ak[i][3] = fmaf(b, xv.w, ak[i][3]);
                }
                xp += TT * VV;
            }
        }
        // store transposed: row = v (length-DD contiguous)
        #pragma unroll
        for (int j = 0; j < 4; ++j) {
            float4 lo = make_float4(aq[0][j], aq[1][j], aq[2][j], aq[3][j]);
            float4 hi = make_float4(aq[4][j], aq[5][j], aq[6][j], aq[7][j]);
            *(float4*)&bufA[(pv + j) * DD + pd]     = lo;
            *(float4*)&bufA[(pv + j) * DD + pd + 4] = hi;
            lo = make_float4(ak[0][j], ak[1][j], ak[2][j], ak[3][j]);
            hi = make_float4(ak[4][j], ak[5][j], ak[6][j], ak[7][j]);
            *(float4*)&bufB[(pv + j) * DD + pd]     = lo;
            *(float4*)&bufB[(pv + j) * DD + pd + 4] = hi;
        }
        __syncthreads();

        // ---------------- scores + softmax (fp32, regs) ----------------
        float s[64];
        #pragma unroll
        for (int w = 0; w < 64; ++w) s[w] = 0.f;
        for (int d4 = 0; d4 < DD / 4; ++d4) {
            const float4 q4 = *(const float4*)&bufA[vq * DD + d4 * 4];
            #pragma unroll
            for (int w = 0; w < 64; ++w) {
                const float4 k4 = *(const float4*)&bufB[(wb + w) * DD + d4 * 4];
                s[w] = fmaf(q4.x, k4.x, s[w]);
                s[w] = fmaf(q4.y, k4.y, s[w]);
                s[w] = fmaf(q4.z, k4.z, s[w]);
                s[w] = fmaf(q4.w, k4.w, s[w]);
            }
        }
        float mx = -3.0e38f;
        #pragma unroll
        for (int w = 0; w < 64; ++w) { s[w] *= 8.0f; mx = fmaxf(mx, s[w]); }
        mx = fmaxf(mx, __shfl_xor(mx, 1));
        float sum = 0.f;
        #pragma unroll
        for (int w = 0; w < 64; ++w) { s[w] = __expf(s[w] - mx); sum += s[w]; }
        sum += __shfl_xor(sum, 1);
        const float inv = 1.0f / sum;
        __syncthreads();   // all reads of qT/kT complete

        // ---------------- V projection -> bufA as vT[w][d] ----------------
        float av[8][4];
        #pragma unroll
        for (int i = 0; i < 8; ++i)
            #pragma unroll
            for (int j = 0; j < 4; ++j) av[i][j] = 0.f;
        {
            const float* xp  = xbase + pv;
            const float* wvp = wv + (size_t)(oc + pd) * CIN;
            for (int c = 0; c < CIN; ++c) {
                const float4 xv = *(const float4*)xp;
                #pragma unroll
                for (int i = 0; i < 8; ++i) {
                    const float a = wvp[i * CIN + c];
                    av[i][0] = fmaf(a, xv.x, av[i][0]);
                    av[i][1] = fmaf(a, xv.y, av[i][1]);
                    av[i][2] = fmaf(a, xv.z, av[i][2]);
                    av[i][3] = fmaf(a, xv.w, av[i][3]);
                }
                xp += TT * VV;
            }
        }
        #pragma unroll
        for (int j = 0; j < 4; ++j) {
            float4 lo = make_float4(av[0][j], av[1][j], av[2][j], av[3][j]);
            float4 hi = make_float4(av[4][j], av[5][j], av[6][j], av[7][j]);
            *(float4*)&bufA[(pv + j) * DD + pd]     = lo;
            *(float4*)&bufA[(pv + j) * DD + pd + 4] = hi;
        }
        __syncthreads();

        // ---------------- P @ V ----------------
        bf16* os = (bf16*)bufB;   // os[d][v], 16 KB, overlays kT (done with it)
        for (int d8 = 0; d8 < DD / 8; ++d8) {
            float acc[8];
            #pragma unroll
            for (int j = 0; j < 8; ++j) acc[j] = 0.f;
            #pragma unroll
            for (int w = 0; w < 64; ++w) {
                const float p = s[w];
                const float* vr = &bufA[(wb + w) * DD + d8 * 8];
                const float4 a = *(const float4*)vr;
                const float4 b = *(const float4*)(vr + 4);
                acc[0] = fmaf(p, a.x, acc[0]);
                acc[1] = fmaf(p, a.y, acc[1]);
                acc[2] = fmaf(p, a.z, acc[2]);
                acc[3] = fmaf(p, a.w, acc[3]);
                acc[4] = fmaf(p, b.x, acc[4]);
                acc[5] = fmaf(p, b.y, acc[5]);
                acc[6] = fmaf(p, b.z, acc[6]);
                acc[7] = fmaf(p, b.w, acc[7]);
            }
            #pragma unroll
            for (int j = 0; j < 8; ++j) acc[j] += __shfl_xor(acc[j], 1);
            if (half == 0) {
                #pragma unroll
                for (int j = 0; j < 8; ++j)
                    os[(d8 * 8 + j) * VV + vq] = __float2bfloat16(acc[j] * inv);
            }
        }
        __syncthreads();

        // ---------------- coalesced bf16 write of o tile ----------------
        bf16* ob = o_ws + ((size_t)(n * OUTC + oc) * TT + (size_t)t) * VV;
        #pragma unroll
        for (int r = 0; r < 4; ++r) {
            const int e = tid * 8 + r * 2048;   // 8 bf16 per thread per iter
            const int d = e >> 7;
            const int v = e & 127;
            *(float4*)&ob[(size_t)d * TT * VV + v] = *(const float4*)&os[e];
        }
        __syncthreads();   // before next head overwrites bufA/bufB
    }
}

// -------------------------------------------------------------------------
// Kernel 2: out[n, o, t, v] = sum_c wp[o,c] * o_arr[n,c,t,v] + bp[o]
// block = (n, t, o-group of 128); 8x8 register tile per thread.
// -------------------------------------------------------------------------
__global__ __launch_bounds__(256, 2)
void out_proj_kernel(const bf16* __restrict__ o_ws,
                     const float* __restrict__ wp,
                     const float* __restrict__ bp,
                     float* __restrict__ out)
{
    __shared__ __align__(16) bf16 otile[128 * VV];   // 32 KB

    const int blk = blockIdx.x;
    const int og  = blk & 3;
    const int t   = (blk >> 2) & 127;
    const int n   = blk >> 9;
    const int tid = threadIdx.x;

    const int v8 = (tid & 15) << 3;              // 8 v cols
    const int ob = og * 128 + (tid >> 4) * 8;    // 8 o rows

    float acc[8][8];
    #pragma unroll
    for (int i = 0; i < 8; ++i)
        #pragma unroll
        for (int j = 0; j < 8; ++j) acc[i][j] = 0.f;

    for (int ct = 0; ct < 4; ++ct) {
        const bf16* src = o_ws + ((size_t)(n * OUTC + ct * 128) * TT + (size_t)t) * VV;
        #pragma unroll
        for (int r = 0; r < 8; ++r) {
            const int e  = tid * 8 + r * 2048;
            const int cl = e >> 7;
            const int v  = e & 127;
            *(float4*)&otile[e] = *(const float4*)&src[(size_t)cl * TT * VV + v];
        }
        __syncthreads();

        const float* wrow = wp + (size_t)ob * OUTC + ct * 128;
        for (int cl = 0; cl < 128; ++cl) {
            union { float4 f4; unsigned short us[8]; } u;
            u.f4 = *(const float4*)&otile[cl * VV + v8];
            float of[8];
            #pragma unroll
            for (int j = 0; j < 8; ++j)
                of[j] = __uint_as_float(((unsigned int)u.us[j]) << 16);
            #pragma unroll
            for (int i = 0; i < 8; ++i) {
                const float w = wrow[(size_t)i * OUTC + cl];
                #pragma unroll
                for (int j = 0; j < 8; ++j)
                    acc[i][j] = fmaf(w, of[j], acc[i][j]);
            }
        }
        __syncthreads();
    }

    #pragma unroll
    for (int i = 0; i < 8; ++i) {
        const float bias = bp[ob + i];
        float* dst = out + ((size_t)(n * OUTC + ob + i) * TT + (size_t)t) * VV + v8;
        float4 r0 = make_float4(acc[i][0] + bias, acc[i][1] + bias,
                                acc[i][2] + bias, acc[i][3] + bias);
        float4 r1 = make_float4(acc[i][4] + bias, acc[i][5] + bias,
                                acc[i][6] + bias, acc[i][7] + bias);
        *(float4*)dst       = r0;
        *(float4*)(dst + 4) = r1;
    }
}

extern "C" void kernel_launch(void* const* d_in, const int* in_sizes, int n_in,
                              void* d_out, int out_size, void* d_ws, size_t ws_size,
                              hipStream_t stream)
{
    const float* x  = (const float*)d_in[0];
    const float* wq = (const float*)d_in[1];
    const float* wk = (const float*)d_in[2];
    const float* wv = (const float*)d_in[3];
    const float* wp = (const float*)d_in[4];
    const float* bp = (const float*)d_in[5];
    float* out = (float*)d_out;
    bf16* o_ws = (bf16*)d_ws;   // needs N*OUT*T*V*2 = 134 MB

    fused_qkv_attn_kernel<<<NN * TT, 256, 0, stream>>>(x, wq, wk, wv, o_ws);
    out_proj_kernel<<<NN * TT * 4, 256, 0, stream>>>(o_ws, wp, bp, out);
}

// Round 2
// 1044.770 us; speedup vs baseline: 4.7949x; 4.7949x over previous
//
#include <hip/hip_runtime.h>
#include <hip/hip_bf16.h>
#include <stddef.h>

#define NN    8
#define CIN   256
#define TT    128
#define VV    128
#define OUTC  512
#define HH    8
#define DD    64

typedef _Float16 f16;
typedef _Float16 f16x8 __attribute__((ext_vector_type(8)));
typedef float    f32x4 __attribute__((ext_vector_type(4)));

#define MFMA16(a, b, c) __builtin_amdgcn_mfma_f32_16x16x32_f16((a), (b), (c), 0, 0, 0)

// ---- workspace layout (bytes) ----
// xe  : (N, T, V, CIN) f16           67,108,864
// wq16: (512, 256) f16 (x8 folded)      262,144
// wk16: (512, 256) f16                  262,144
// wv16: (512, 256) f16                  262,144
// wp16: (512, 512) f16                  524,288
// oe  : (N, T, V, OUT) f16          134,217,728   -> total 202,637,312
#define XE_OFF   ((size_t)0)
#define WQ_OFF   ((size_t)67108864)
#define WK_OFF   ((size_t)67371008)
#define WV_OFF   ((size_t)67633152)
#define WP_OFF   ((size_t)67895296)
#define OE_OFF   ((size_t)68419584)

// -------------------------------------------------------------------------
// Kernel A: blocks 0..1023 transpose+convert x (n,c,t,v) fp32 -> xe (n,t,v,c) f16
//           blocks 1024..1039 convert weights fp32 -> f16 (wq scaled by 8)
// -------------------------------------------------------------------------
__global__ __launch_bounds__(256, 2)
void prep_kernel(const float* __restrict__ x,
                 const float* __restrict__ wq,
                 const float* __restrict__ wk,
                 const float* __restrict__ wv,
                 const float* __restrict__ wp,
                 f16* __restrict__ xe,
                 f16* __restrict__ wq16, f16* __restrict__ wk16,
                 f16* __restrict__ wv16, f16* __restrict__ wp16)
{
    const int bid = blockIdx.x;
    const int tid = threadIdx.x;

    if (bid < NN * TT) {
        __shared__ f16 tile[128 * 136];   // (c_local, v), stride 136
        const int n = bid >> 7;
        const int t = bid & 127;

        for (int p = 0; p < 2; ++p) {
            // ---- load 128c x 128v fp32, convert, write tile (b64-packed) ----
            #pragma unroll
            for (int it = 0; it < 4; ++it) {
                const int cl = it * 32 + (tid >> 3);        // 0..127
                const int c  = p * 128 + cl;
                const int v0 = (tid & 7) * 16;
                const float* src = x + (((size_t)(n * CIN + c) * TT + t) * VV) + v0;
                #pragma unroll
                for (int q = 0; q < 4; ++q) {
                    const float4 xv = *(const float4*)(src + q * 4);
                    union { uint2 u; f16 h[4]; } pk;
                    pk.h[0] = (f16)xv.x; pk.h[1] = (f16)xv.y;
                    pk.h[2] = (f16)xv.z; pk.h[3] = (f16)xv.w;
                    *(uint2*)&tile[cl * 136 + v0 + q * 4] = pk.u;
                }
            }
            __syncthreads();
            // ---- write xe rows: thread -> (v = tid>>1, half = tid&1) ----
            {
                const int v  = tid >> 1;
                const int ch = tid & 1;
                f16* dst = xe + ((size_t)(n * TT + t) * VV + v) * 256 + p * 128 + ch * 64;
                #pragma unroll
                for (int q8 = 0; q8 < 8; ++q8) {
                    union { int4 u; f16 h[8]; } pk;
                    #pragma unroll
                    for (int s = 0; s < 8; ++s)
                        pk.h[s] = tile[(ch * 64 + q8 * 8 + s) * 136 + v];
                    *(int4*)(dst + q8 * 8) = pk.u;
                }
            }
            __syncthreads();
        }
    } else {
        // weight conversion: 655360 fp32 values -> f16
        const int gid = (bid - NN * TT) * 256 + tid;   // 0..4095
        for (int i = gid; i < 163840; i += 4096) {
            const int e = i * 4;
            union { uint2 u; f16 h[4]; } pk;
            if (e < 131072) {
                const float4 v = *(const float4*)(wq + e);
                pk.h[0] = (f16)(v.x * 8.0f); pk.h[1] = (f16)(v.y * 8.0f);
                pk.h[2] = (f16)(v.z * 8.0f); pk.h[3] = (f16)(v.w * 8.0f);
                *(uint2*)(wq16 + e) = pk.u;
            } else if (e < 262144) {
                const float4 v = *(const float4*)(wk + (e - 131072));
                pk.h[0] = (f16)v.x; pk.h[1] = (f16)v.y; pk.h[2] = (f16)v.z; pk.h[3] = (f16)v.w;
                *(uint2*)(wk16 + (e - 131072)) = pk.u;
            } else if (e < 393216) {
                const float4 v = *(const float4*)(wv + (e - 262144));
                pk.h[0] = (f16)v.x; pk.h[1] = (f16)v.y; pk.h[2] = (f16)v.z; pk.h[3] = (f16)v.w;
                *(uint2*)(wv16 + (e - 262144)) = pk.u;
            } else {
                const float4 v = *(const float4*)(wp + (e - 393216));
                pk.h[0] = (f16)v.x; pk.h[1] = (f16)v.y; pk.h[2] = (f16)v.z; pk.h[3] = (f16)v.w;
                *(uint2*)(wp16 + (e - 393216)) = pk.u;
            }
        }
    }
}

// -------------------------------------------------------------------------
// Kernel B: one block per (n,t,h). QKV projection (MFMA, frags direct from
// global) -> LDS layout transpose -> QK^T (S^T orientation) -> in-register
// softmax -> P to LDS -> PV -> oe (n,t,v,out) f16.
// -------------------------------------------------------------------------
__global__ __launch_bounds__(256, 2)
void qkv_attn_kernel(const f16* __restrict__ xe,
                     const f16* __restrict__ wq16,
                     const f16* __restrict__ wk16,
                     const f16* __restrict__ wv16,
                     f16* __restrict__ oe)
{
    // sQ: (v,128 x 72) | sK: same | sVT: (d,64 x 136). sP aliases sQ+sK.
    __shared__ f16 smem[27136];
    f16* sQ  = smem;              // 9216 halves
    f16* sK  = smem + 9216;       // 9216 halves
    f16* sVT = smem + 18432;      // 8704 halves
    f16* sP  = smem;              // 17408 halves (aliases sQ,sK)

    const int tid = threadIdx.x;
    const int wid = tid >> 6;
    const int l   = tid & 63;
    const int r   = l & 15;
    const int g   = l >> 4;

    const int bid = blockIdx.x;
    const int h = bid & 7;
    const int t = (bid >> 3) & 127;
    const int n = bid >> 10;

    const f16* xrow = xe + (size_t)(n * TT + t) * VV * 256;   // [v][c]

    // ---------------- Phase 1a: q,k projection ----------------
    f32x4 accq[4][2], acck[4][2];
    #pragma unroll
    for (int dt = 0; dt < 4; ++dt)
        #pragma unroll
        for (int vt = 0; vt < 2; ++vt) { accq[dt][vt] = (f32x4)0.0f; acck[dt][vt] = (f32x4)0.0f; }

    for (int ks = 0; ks < 8; ++ks) {
        const int ko = ks * 32 + g * 8;
        f16x8 aq[4], ak[4], bx[2];
        #pragma unroll
        for (int dt = 0; dt < 4; ++dt) {
            aq[dt] = *(const f16x8*)(wq16 + (size_t)(h * 64 + dt * 16 + r) * 256 + ko);
            ak[dt] = *(const f16x8*)(wk16 + (size_t)(h * 64 + dt * 16 + r) * 256 + ko);
        }
        #pragma unroll
        for (int vt = 0; vt < 2; ++vt)
            bx[vt] = *(const f16x8*)(xrow + (size_t)(wid * 32 + vt * 16 + r) * 256 + ko);
        #pragma unroll
        for (int dt = 0; dt < 4; ++dt)
            #pragma unroll
            for (int vt = 0; vt < 2; ++vt) {
                accq[dt][vt] = MFMA16(aq[dt], bx[vt], accq[dt][vt]);
                acck[dt][vt] = MFMA16(ak[dt], bx[vt], acck[dt][vt]);
            }
    }
    // write q,k transposed to (v, d) — packed b64
    #pragma unroll
    for (int dt = 0; dt < 4; ++dt)
        #pragma unroll
        for (int vt = 0; vt < 2; ++vt) {
            const int v = wid * 32 + vt * 16 + r;
            union { uint2 u; f16 h4[4]; } pq, pk;
            #pragma unroll
            for (int i = 0; i < 4; ++i) {
                pq.h4[i] = (f16)accq[dt][vt][i];
                pk.h4[i] = (f16)acck[dt][vt][i];
            }
            *(uint2*)&sQ[v * 72 + dt * 16 + g * 4] = pq.u;
            *(uint2*)&sK[v * 72 + dt * 16 + g * 4] = pk.u;
        }

    // ---------------- Phase 1b: v projection ----------------
    f32x4 accv[4][2];
    #pragma unroll
    for (int dt = 0; dt < 4; ++dt)
        #pragma unroll
        for (int wt = 0; wt < 2; ++wt) accv[dt][wt] = (f32x4)0.0f;

    for (int ks = 0; ks < 8; ++ks) {
        const int ko = ks * 32 + g * 8;
        f16x8 av[4], bx[2];
        #pragma unroll
        for (int dt = 0; dt < 4; ++dt)
            av[dt] = *(const f16x8*)(wv16 + (size_t)(h * 64 + dt * 16 + r) * 256 + ko);
        #pragma unroll
        for (int wt = 0; wt < 2; ++wt)
            bx[wt] = *(const f16x8*)(xrow + (size_t)(wid * 32 + wt * 16 + r) * 256 + ko);
        #pragma unroll
        for (int dt = 0; dt < 4; ++dt)
            #pragma unroll
            for (int wt = 0; wt < 2; ++wt)
                accv[dt][wt] = MFMA16(av[dt], bx[wt], accv[dt][wt]);
    }
    // write V^T (d, w) — column scatter b16
    #pragma unroll
    for (int dt = 0; dt < 4; ++dt)
        #pragma unroll
        for (int wt = 0; wt < 2; ++wt) {
            const int w = wid * 32 + wt * 16 + r;
            #pragma unroll
            for (int i = 0; i < 4; ++i)
                sVT[(dt * 16 + g * 4 + i) * 136 + w] = (f16)accv[dt][wt][i];
        }
    __syncthreads();

    // ---------------- Phase 2: S^T = K Q^T (w x v), scale already in wq ----
    f32x4 sT[8][2];
    #pragma unroll
    for (int mt = 0; mt < 8; ++mt)
        #pragma unroll
        for (int vt = 0; vt < 2; ++vt) sT[mt][vt] = (f32x4)0.0f;

    #pragma unroll
    for (int ks = 0; ks < 2; ++ks) {
        const int ko = ks * 32 + g * 8;
        f16x8 bq[2];
        #pragma unroll
        for (int vt = 0; vt < 2; ++vt)
            bq[vt] = *(const f16x8*)&sQ[(wid * 32 + vt * 16 + r) * 72 + ko];
        #pragma unroll
        for (int mt = 0; mt < 8; ++mt) {
            const f16x8 a = *(const f16x8*)&sK[(mt * 16 + r) * 72 + ko];
            #pragma unroll
            for (int vt = 0; vt < 2; ++vt)
                sT[mt][vt] = MFMA16(a, bq[vt], sT[mt][vt]);
        }
    }

    // ---------------- Phase 3: softmax over w (in-register) ----------------
    float inv[2];
    #pragma unroll
    for (int vt = 0; vt < 2; ++vt) {
        float mx = -3.0e38f;
        #pragma unroll
        for (int mt = 0; mt < 8; ++mt)
            #pragma unroll
            for (int i = 0; i < 4; ++i) mx = fmaxf(mx, sT[mt][vt][i]);
        mx = fmaxf(mx, __shfl_xor(mx, 16));
        mx = fmaxf(mx, __shfl_xor(mx, 32));
        float sm = 0.0f;
        #pragma unroll
        for (int mt = 0; mt < 8; ++mt)
            #pragma unroll
            for (int i = 0; i < 4; ++i) {
                const float e = __expf(sT[mt][vt][i] - mx);
                sT[mt][vt][i] = e;
                sm += e;
            }
        sm += __shfl_xor(sm, 16);
        sm += __shfl_xor(sm, 32);
        inv[vt] = 1.0f / sm;
    }
    __syncthreads();   // all QK reads done before P overwrites sQ/sK

    #pragma unroll
    for (int mt = 0; mt < 8; ++mt)
        #pragma unroll
        for (int vt = 0; vt < 2; ++vt) {
            const int v = wid * 32 + vt * 16 + r;
            union { uint2 u; f16 h4[4]; } pk;
            #pragma unroll
            for (int i = 0; i < 4; ++i) pk.h4[i] = (f16)sT[mt][vt][i];
            *(uint2*)&sP[v * 136 + mt * 16 + g * 4] = pk.u;
        }
    __syncthreads();

    // ---------------- Phase 4: o^T = V^T P^T (d x v) ----------------
    f32x4 oT[4][2];
    #pragma unroll
    for (int dt = 0; dt < 4; ++dt)
        #pragma unroll
        for (int vt = 0; vt < 2; ++vt) oT[dt][vt] = (f32x4)0.0f;

    #pragma unroll
    for (int ks = 0; ks < 4; ++ks) {
        const int ko = ks * 32 + g * 8;
        f16x8 bp_[2];
        #pragma unroll
        for (int vt = 0; vt < 2; ++vt)
            bp_[vt] = *(const f16x8*)&sP[(wid * 32 + vt * 16 + r) * 136 + ko];
        #pragma unroll
        for (int dt = 0; dt < 4; ++dt) {
            const f16x8 a = *(const f16x8*)&sVT[(dt * 16 + r) * 136 + ko];
            #pragma unroll
            for (int vt = 0; vt < 2; ++vt)
                oT[dt][vt] = MFMA16(a, bp_[vt], oT[dt][vt]);
        }
    }

    // epilogue: normalize, store to oe (n,t,v, h*64+d) — packed b64
    #pragma unroll
    for (int dt = 0; dt < 4; ++dt)
        #pragma unroll
        for (int vt = 0; vt < 2; ++vt) {
            const int v = wid * 32 + vt * 16 + r;
            union { uint2 u; f16 h4[4]; } pk;
            #pragma unroll
            for (int i = 0; i < 4; ++i) pk.h4[i] = (f16)(oT[dt][vt][i] * inv[vt]);
            f16* dst = oe + ((size_t)(n * TT + t) * VV + v) * 512 + h * 64 + dt * 16 + g * 4;
            *(uint2*)dst = pk.u;
        }
}

// -------------------------------------------------------------------------
// Kernel C: out[n,o,t,v] = wp @ o + bp. One block per (n, t, og), og in 0..1
// (256 o-rows). All fragments direct from global (wp16 L2-resident, oe slice
// L1/L2). fp32 epilogue with bias.
// -------------------------------------------------------------------------
__global__ __launch_bounds__(256, 2)
void out_proj_kernel(const f16* __restrict__ oe,
                     const f16* __restrict__ wp16,
                     const float* __restrict__ bp,
                     float* __restrict__ out)
{
    const int tid = threadIdx.x;
    const int wid = tid >> 6;
    const int l   = tid & 63;
    const int r   = l & 15;
    const int g   = l >> 4;

    const int bid = blockIdx.x;
    const int og = bid & 1;
    const int t  = (bid >> 1) & 127;
    const int n  = bid >> 8;

    const f16* brow = oe + (size_t)(n * TT + t) * VV * 512;   // [v][c]

    f32x4 acc[4][8];
    #pragma unroll
    for (int mi = 0; mi < 4; ++mi)
        #pragma unroll
        for (int nt = 0; nt < 8; ++nt) acc[mi][nt] = (f32x4)0.0f;

    for (int ks = 0; ks < 16; ++ks) {
        const int ko = ks * 32 + g * 8;
        f16x8 a[4], b[8];
        #pragma unroll
        for (int mi = 0; mi < 4; ++mi)
            a[mi] = *(const f16x8*)(wp16 + (size_t)(og * 256 + (wid * 4 + mi) * 16 + r) * 512 + ko);
        #pragma unroll
        for (int nt = 0; nt < 8; ++nt)
            b[nt] = *(const f16x8*)(brow + (size_t)(nt * 16 + r) * 512 + ko);
        #pragma unroll
        for (int mi = 0; mi < 4; ++mi)
            #pragma unroll
            for (int nt = 0; nt < 8; ++nt)
                acc[mi][nt] = MFMA16(a[mi], b[nt], acc[mi][nt]);
    }

    #pragma unroll
    for (int mi = 0; mi < 4; ++mi) {
        const int obase = og * 256 + (wid * 4 + mi) * 16 + g * 4;
        const float b0 = bp[obase + 0];
        const float b1 = bp[obase + 1];
        const float b2 = bp[obase + 2];
        const float b3 = bp[obase + 3];
        #pragma unroll
        for (int nt = 0; nt < 8; ++nt) {
            const int v = nt * 16 + r;
            float* dst = out + ((size_t)(n * OUTC + obase) * TT + t) * VV + v;
            dst[0 * TT * VV] = acc[mi][nt][0] + b0;
            dst[1 * TT * VV] = acc[mi][nt][1] + b1;
            dst[2 * TT * VV] = acc[mi][nt][2] + b2;
            dst[3 * TT * VV] = acc[mi][nt][3] + b3;
        }
    }
}

extern "C" void kernel_launch(void* const* d_in, const int* in_sizes, int n_in,
                              void* d_out, int out_size, void* d_ws, size_t ws_size,
                              hipStream_t stream)
{
    const float* x  = (const float*)d_in[0];
    const float* wq = (const float*)d_in[1];
    const float* wk = (const float*)d_in[2];
    const float* wv = (const float*)d_in[3];
    const float* wp = (const float*)d_in[4];
    const float* bp = (const float*)d_in[5];
    float* out = (float*)d_out;

    char* ws = (char*)d_ws;
    f16* xe   = (f16*)(ws + XE_OFF);
    f16* wq16 = (f16*)(ws + WQ_OFF);
    f16* wk16 = (f16*)(ws + WK_OFF);
    f16* wv16 = (f16*)(ws + WV_OFF);
    f16* wp16 = (f16*)(ws + WP_OFF);
    f16* oe   = (f16*)(ws + OE_OFF);

    prep_kernel<<<NN * TT + 16, 256, 0, stream>>>(x, wq, wk, wv, wp, xe, wq16, wk16, wv16, wp16);
    qkv_attn_kernel<<<NN * TT * HH, 256, 0, stream>>>(xe, wq16, wk16, wv16, oe);
    out_proj_kernel<<<NN * TT * 2, 256, 0, stream>>>(oe, wp16, bp, out);
}